// Round 5
// baseline (20110.968 us; speedup 1.0000x reference)
//
#include <hip/hip_runtime.h>
#include <hip/hip_bf16.h>
#include <stdint.h>

// Problem constants
#define T_STEPS 128
#define BATCH   2048
#define IN_DIM  18
#define HID     256
#define G3      768

// Fragment layout (same repack as R3/R4)
#define NT   48
#define KT0  9               // layer0: 1 (x pad32) + 8 (h1)
#define KT1  16              // layer1: 8 (W_ih1) + 8 (W_hh1)
#define L0_FRAGS (NT * KT0)  // 432
#define L1_FRAGS (NT * KT1)  // 768
#define TOT_FRAGS (L0_FRAGS + L1_FRAGS)  // 1200 x 1KB

// Weight-stationary grid: 64 groups (32 rows each) x 4 slices (64 h-cols each)
#define NBLK 256
#define TPB  768             // 12 waves: wave = gate(3) x col-tile(4)
#define PITCH0 296
#define PITCH1 552

// d_ws layout
#define FLAGS_OFF  1310720u                 // 1.25 MB (wq ends at 1.2288 MB)
#define N_FLAGS    (T_STEPS * 2 * 64 * 4)   // 65536
#define HX_OFF     1572864u                 // 1.5 MB; 1 Mi uints = 4 MB

typedef unsigned short ushort_t;
using frag_ab = __attribute__((ext_vector_type(8))) short;
using f32x4   = __attribute__((ext_vector_type(4))) float;

__device__ __forceinline__ unsigned short f2bf(float f) {
  unsigned int u = __float_as_uint(f);
  u = (u + 0x7fffu + ((u >> 16) & 1u)) >> 16;  // RNE
  return (unsigned short)u;
}
__device__ __forceinline__ float sigmoidf_(float v) {
  return 1.f / (1.f + __expf(-v));
}
__device__ __forceinline__ float tanhf_(float v) {
  float a = fabsf(v);
  float e = __expf(-2.f * a);
  float r = (1.f - e) / (1.f + e);
  return v < 0.f ? -r : r;
}
__device__ __forceinline__ f32x4 mfma16(frag_ab a, frag_ab b, f32x4 c) {
  return __builtin_amdgcn_mfma_f32_16x16x32_bf16(a, b, c, 0, 0, 0);
}

// ---------------------------------------------------------------------------
// Prologue 1: fp32 weights -> bf16 MFMA B-fragments (unchanged from R3/R4).
// ---------------------------------------------------------------------------
__global__ __launch_bounds__(256) void repack_w(
    const float* __restrict__ Wih0, const float* __restrict__ Whh0,
    const float* __restrict__ Wih1, const float* __restrict__ Whh1,
    unsigned short* __restrict__ wq)
{
  int g = blockIdx.x * 256 + threadIdx.x;
  if (g >= TOT_FRAGS * 64) return;
  int f = g >> 6;
  int L = g & 63;
  int q = L >> 4, c16 = L & 15;
  unsigned short v[8];
  if (f < L0_FRAGS) {
    int n = f / KT0, kt = f - n * KT0;
    int col = n * 16 + c16;
    if (kt == 0) {
      #pragma unroll
      for (int j = 0; j < 8; ++j) {
        int k = q * 8 + j;
        v[j] = (k < IN_DIM) ? f2bf(Wih0[col * IN_DIM + k]) : (unsigned short)0;
      }
    } else {
      int kb = (kt - 1) * 32 + q * 8;
      #pragma unroll
      for (int j = 0; j < 8; ++j) v[j] = f2bf(Whh0[col * HID + kb + j]);
    }
  } else {
    int f1 = f - L0_FRAGS;
    int n = f1 / KT1, kt = f1 - n * KT1;
    int col = n * 16 + c16;
    const float* __restrict__ W = (kt < 8) ? Wih1 : Whh1;
    int kb = (kt & 7) * 32 + q * 8;
    #pragma unroll
    for (int j = 0; j < 8; ++j) v[j] = f2bf(W[col * HID + kb + j]);
  }
  frag_ab pv;
  #pragma unroll
  for (int j = 0; j < 8; ++j) pv[j] = (short)v[j];
  *(frag_ab*)((char*)wq + ((size_t)f << 10) + (size_t)(L << 4)) = pv;
}

// ---------------------------------------------------------------------------
// Prologue 2: zero the cross-block flags (d_ws is poisoned each launch).
// ---------------------------------------------------------------------------
__global__ __launch_bounds__(256) void clear_flags_k(uint32_t* __restrict__ f) {
  int i = blockIdx.x * 256 + threadIdx.x;
  if (i < N_FLAGS) f[i] = 0;
}

// ---------------------------------------------------------------------------
// Weight-stationary fused GRU. 256 blocks = 64 groups x 4 slices.
// Weights live in VGPRs for the whole kernel; per-step the 4 slices of a
// group exchange h-slices through global memory (release/acquire + flags).
// ---------------------------------------------------------------------------
__global__ __launch_bounds__(TPB, 3) void gru_ws(
    const float* __restrict__ x,
    const float* __restrict__ bih0, const float* __restrict__ bhh0,
    const float* __restrict__ bih1, const float* __restrict__ bhh1,
    const float* __restrict__ fcw,  const float* __restrict__ fcb,
    const unsigned short* __restrict__ wq,
    uint32_t* __restrict__ flags,
    uint32_t* __restrict__ hxu,
    float* __restrict__ out)
{
  __shared__ __align__(16) unsigned short A0[32][PITCH0]; // [x pad32 | h1(256)]
  __shared__ __align__(16) unsigned short A1[32][PITCH1]; // [h1_new | h2 | pad]
  __shared__ f32x4 red[2][4][2][64];                      // r/z accums -> n-wave
  __shared__ float pad[4096];                             // LDS pad: 1 block/CU

  const int tid   = threadIdx.x;
  const int wave  = tid >> 6;          // 0..11
  const int lane  = tid & 63;
  const int q     = lane >> 4;
  const int c16   = lane & 15;
  const int g     = wave >> 2;         // 0=r, 1=z, 2=n
  const int ct    = wave & 3;          // col-tile within slice
  const int group = blockIdx.x & 63;   // batch-row group (32 rows)
  const int slice = blockIdx.x >> 6;   // h-col slice (64 cols)
  const int brow0 = group * 32;
  const int colL  = ct * 16 + c16;     // local col in slice
  const int c     = slice * 64 + colL; // global h-col
  const int ntile = g * 16 + slice * 4 + ct;

  // ---- zero LDS (h parts and x pad stay 0), touch pad so it's allocated ----
  for (int i = tid; i < 32 * PITCH0; i += TPB) (&A0[0][0])[i] = 0;
  for (int i = tid; i < 32 * PITCH1; i += TPB) (&A1[0][0])[i] = 0;
  ((volatile float*)pad)[tid] = 0.f;

  // ---- preload this wave's 25 weight fragments into registers ----
  const char* wb = (const char*)wq;
  frag_ab w0[KT0], w1[KT1];
  #pragma unroll
  for (int i = 0; i < KT0; ++i)
    w0[i] = *(const frag_ab*)(wb + ((size_t)(ntile * KT0 + i) << 10) + (size_t)(lane << 4));
  #pragma unroll
  for (int i = 0; i < KT1; ++i)
    w1[i] = *(const frag_ab*)(wb + ((size_t)(L0_FRAGS + ntile * KT1 + i) << 10) + (size_t)(lane << 4));

  // ---- biases (only the n-waves run the epilogue) ----
  float b_rc0 = 0.f, b_zc0 = 0.f, b_ni0 = 0.f, b_nh0 = 0.f;
  float b_rc1 = 0.f, b_zc1 = 0.f, b_ni1 = 0.f, b_nh1 = 0.f;
  if (g == 2) {
    b_rc0 = bih0[c] + bhh0[c];
    b_zc0 = bih0[HID + c] + bhh0[HID + c];
    b_ni0 = bih0[2 * HID + c];
    b_nh0 = bhh0[2 * HID + c];
    b_rc1 = bih1[c] + bhh1[c];
    b_zc1 = bih1[HID + c] + bhh1[HID + c];
    b_ni1 = bih1[2 * HID + c];
    b_nh1 = bhh1[2 * HID + c];
  }

  // ---- stage x_0 ----
  if (tid < 32 * IN_DIM) {
    int r = tid / IN_DIM, cc = tid - r * IN_DIM;
    A0[r][cc] = f2bf(x[(size_t)(brow0 + r) * IN_DIM + cc]);
  }
  __syncthreads();

  float h1m[2][4] = {{0,0,0,0},{0,0,0,0}};
  float h2m[2][4] = {{0,0,0,0},{0,0,0,0}};
  f32x4 anx[2], anh[2];
  int deadq = 0;

  for (int t = 0; t < T_STEPS; ++t) {
    const uint32_t par = (uint32_t)(t & 1);

    // ======================= Layer 0 =======================
    #pragma unroll
    for (int rt = 0; rt < 2; ++rt) {
      f32x4 aA = {0,0,0,0}, aB = {0,0,0,0};
      #pragma unroll
      for (int kt = 0; kt < KT0; ++kt) {
        const frag_ab a = *(const frag_ab*)&A0[rt * 16 + c16][kt * 32 + q * 8];
        if (g == 2) { if (kt == 0) aA = mfma16(a, w0[kt], aA);
                      else         aB = mfma16(a, w0[kt], aB); }
        else aA = mfma16(a, w0[kt], aA);
      }
      if (g < 2) red[g][ct][rt][lane] = aA;
      else { anx[rt] = aA; anh[rt] = aB; }
    }
    __syncthreads();   // B1: red ready; A0 reads done

    if (g == 2) {      // epilogue + local writes + exchange-out (h1)
      const uint32_t hb = ((((uint32_t)group * 2u + par) * 2u + 0u) * 4u + (uint32_t)slice) * 1024u;
      #pragma unroll
      for (int rt = 0; rt < 2; ++rt) {
        const f32x4 ar = red[0][ct][rt][lane];
        const f32x4 az = red[1][ct][rt][lane];
        unsigned short hbv[4];
        #pragma unroll
        for (int rr = 0; rr < 4; ++rr) {
          const int row = rt * 16 + q * 4 + rr;
          float rg = sigmoidf_(ar[rr] + b_rc0);
          float zg = sigmoidf_(az[rr] + b_zc0);
          float ng = tanhf_(anx[rt][rr] + b_ni0 + rg * (anh[rt][rr] + b_nh0));
          float hnew = (1.f - zg) * ng + zg * h1m[rt][rr];
          h1m[rt][rr] = hnew;
          unsigned short hv = f2bf(hnew);
          hbv[rr] = hv;
          A0[row][32 + c] = hv;   // next step's L0 A (local cols)
          A1[row][c]      = hv;   // this step's L1 A (local cols)
        }
        uint2 u;
        u.x = (uint32_t)hbv[0] | ((uint32_t)hbv[1] << 16);
        u.y = (uint32_t)hbv[2] | ((uint32_t)hbv[3] << 16);
        *(uint2*)&hxu[hb + (uint32_t)(colL * 16 + rt * 8 + q * 2)] = u;
      }
      __threadfence();
    }
    __syncthreads();   // B2: hx stores fenced; flag can be published
    if (tid == 0) {
      const uint32_t fb = ((uint32_t)(t * 2 + 0) * 64u + group) * 4u;
      __hip_atomic_store(&flags[fb + slice], 1u, __ATOMIC_RELEASE, __HIP_MEMORY_SCOPE_AGENT);
      #pragma unroll
      for (int s2 = 0; s2 < 4; ++s2) if (s2 != slice) {
        int it = 0, bound = deadq ? 64 : (1 << 22);
        while (__hip_atomic_load(&flags[fb + s2], __ATOMIC_ACQUIRE, __HIP_MEMORY_SCOPE_AGENT) == 0) {
          if (++it >= bound) { deadq = 1; break; }
          __builtin_amdgcn_s_sleep(1);
        }
      }
    }
    __syncthreads();   // B3: flags observed
    __threadfence();   // acquire: invalidate stale cache lines
    {                  // copy-in remote h1 slices (3 x 64 cols x 32 rows)
      const uint32_t hb = (((uint32_t)group * 2u + par) * 2u + 0u) * 4u * 1024u;
      const int srel = tid >> 8;                 // 0..2
      const int rem4 = (tid & 255) * 4;          // uint offset in chunk
      const int sp = srel + (srel >= slice);
      const uint4 u4 = *(const uint4*)&hxu[hb + (uint32_t)sp * 1024u + rem4];
      const int cg = sp * 64 + (rem4 >> 4);
      const int r0 = (rem4 & 15) * 2;
      const uint32_t uu[4] = {u4.x, u4.y, u4.z, u4.w};
      #pragma unroll
      for (int j = 0; j < 4; ++j) {
        unsigned short lo = (unsigned short)(uu[j] & 0xffffu);
        unsigned short hi = (unsigned short)(uu[j] >> 16);
        A0[r0 + 2*j][32 + cg] = lo;  A0[r0 + 2*j + 1][32 + cg] = hi;
        A1[r0 + 2*j][cg]      = lo;  A1[r0 + 2*j + 1][cg]      = hi;
      }
    }
    __syncthreads();   // B4: A1 fully staged

    // ======================= Layer 1 =======================
    #pragma unroll
    for (int rt = 0; rt < 2; ++rt) {
      f32x4 aA = {0,0,0,0}, aB = {0,0,0,0};
      #pragma unroll
      for (int kt = 0; kt < KT1; ++kt) {
        const frag_ab a = *(const frag_ab*)&A1[rt * 16 + c16][kt * 32 + q * 8];
        if (g == 2) { if (kt < 8) aA = mfma16(a, w1[kt], aA);
                      else        aB = mfma16(a, w1[kt], aB); }
        else aA = mfma16(a, w1[kt], aA);
      }
      if (g < 2) red[g][ct][rt][lane] = aA;
      else { anx[rt] = aA; anh[rt] = aB; }
    }
    __syncthreads();   // B1'

    if (g == 2) {
      const uint32_t hb = ((((uint32_t)group * 2u + par) * 2u + 1u) * 4u + (uint32_t)slice) * 1024u;
      #pragma unroll
      for (int rt = 0; rt < 2; ++rt) {
        const f32x4 ar = red[0][ct][rt][lane];
        const f32x4 az = red[1][ct][rt][lane];
        unsigned short hbv[4];
        #pragma unroll
        for (int rr = 0; rr < 4; ++rr) {
          const int row = rt * 16 + q * 4 + rr;
          float rg = sigmoidf_(ar[rr] + b_rc1);
          float zg = sigmoidf_(az[rr] + b_zc1);
          float ng = tanhf_(anx[rt][rr] + b_ni1 + rg * (anh[rt][rr] + b_nh1));
          float hnew = (1.f - zg) * ng + zg * h2m[rt][rr];
          h2m[rt][rr] = hnew;
          unsigned short hv = f2bf(hnew);
          hbv[rr] = hv;
          A1[row][HID + c] = hv;   // next step's L1 A h2 part (local cols)
        }
        uint2 u;
        u.x = (uint32_t)hbv[0] | ((uint32_t)hbv[1] << 16);
        u.y = (uint32_t)hbv[2] | ((uint32_t)hbv[3] << 16);
        *(uint2*)&hxu[hb + (uint32_t)(colL * 16 + rt * 8 + q * 2)] = u;
      }
      __threadfence();
    }
    __syncthreads();   // B2'
    if (tid == 0) {
      const uint32_t fb = ((uint32_t)(t * 2 + 1) * 64u + group) * 4u;
      __hip_atomic_store(&flags[fb + slice], 1u, __ATOMIC_RELEASE, __HIP_MEMORY_SCOPE_AGENT);
      #pragma unroll
      for (int s2 = 0; s2 < 4; ++s2) if (s2 != slice) {
        int it = 0, bound = deadq ? 64 : (1 << 22);
        while (__hip_atomic_load(&flags[fb + s2], __ATOMIC_ACQUIRE, __HIP_MEMORY_SCOPE_AGENT) == 0) {
          if (++it >= bound) { deadq = 1; break; }
          __builtin_amdgcn_s_sleep(1);
        }
      }
    }
    __syncthreads();   // B3'
    __threadfence();
    {                  // copy-in remote h2 slices
      const uint32_t hb = ((((uint32_t)group * 2u + par) * 2u + 1u) * 4u) * 1024u;
      const int srel = tid >> 8;
      const int rem4 = (tid & 255) * 4;
      const int sp = srel + (srel >= slice);
      const uint4 u4 = *(const uint4*)&hxu[hb + (uint32_t)sp * 1024u + rem4];
      const int cg = sp * 64 + (rem4 >> 4);
      const int r0 = (rem4 & 15) * 2;
      const uint32_t uu[4] = {u4.x, u4.y, u4.z, u4.w};
      #pragma unroll
      for (int j = 0; j < 4; ++j) {
        A1[r0 + 2*j][HID + cg]     = (unsigned short)(uu[j] & 0xffffu);
        A1[r0 + 2*j + 1][HID + cg] = (unsigned short)(uu[j] >> 16);
      }
    }
    // stage x_{t+1} (safe: this step's L0 reads are long done)
    if (t + 1 < T_STEPS && tid < 32 * IN_DIM) {
      int r = tid / IN_DIM, cc = tid - r * IN_DIM;
      A0[r][cc] = f2bf(x[(size_t)((t + 1) * BATCH + brow0 + r) * IN_DIM + cc]);
    }
    __syncthreads();   // B4': ready for next step
  }

  // ---- FC head (slice 0 only; full h2 is staged in A1[:, 256:512]) ----
  if (slice == 0 && tid < 32 * 4) {
    int row = tid >> 2, o = tid & 3;
    const float* wrow = &fcw[o * HID];
    float acc = fcb[o];
    #pragma unroll 8
    for (int k = 0; k < HID; ++k) {
      uint32_t u = (uint32_t)A1[row][HID + k] << 16;
      acc += __uint_as_float(u) * wrow[k];
    }
    float sg = 1.f / (1.f + __expf(-acc));
    out[(size_t)(brow0 + row) * 4 + o] = sg * 2.f - 1.f;
  }
}

extern "C" void kernel_launch(void* const* d_in, const int* in_sizes, int n_in,
                              void* d_out, int out_size, void* d_ws, size_t ws_size,
                              hipStream_t stream) {
  const float* x    = (const float*)d_in[0];
  const float* Wih0 = (const float*)d_in[1];
  const float* Whh0 = (const float*)d_in[2];
  const float* bih0 = (const float*)d_in[3];
  const float* bhh0 = (const float*)d_in[4];
  const float* Wih1 = (const float*)d_in[5];
  const float* Whh1 = (const float*)d_in[6];
  const float* bih1 = (const float*)d_in[7];
  const float* bhh1 = (const float*)d_in[8];
  const float* fcw  = (const float*)d_in[9];
  const float* fcb  = (const float*)d_in[10];

  unsigned short* wq = (unsigned short*)d_ws;
  uint32_t* flags = (uint32_t*)((char*)d_ws + FLAGS_OFF);
  uint32_t* hxu   = (uint32_t*)((char*)d_ws + HX_OFF);

  repack_w<<<(TOT_FRAGS * 64 + 255) / 256, 256, 0, stream>>>(Wih0, Whh0, Wih1, Whh1, wq);
  clear_flags_k<<<(N_FLAGS + 255) / 256, 256, 0, stream>>>(flags);
  gru_ws<<<NBLK, TPB, 0, stream>>>(x, bih0, bhh0, bih1, bhh1, fcw, fcb, wq,
                                   flags, hxu, (float*)d_out);
}

// Round 6
// 3059.540 us; speedup vs baseline: 6.5732x; 6.5732x over previous
//
#include <hip/hip_runtime.h>
#include <hip/hip_bf16.h>
#include <stdint.h>

// Problem constants
#define T_STEPS 128
#define BATCH   2048
#define IN_DIM  18
#define HID     256
#define G3      768

// Tiling
#define NT   48
#define KT0  9               // layer0: 1 (x pad32) + 8 (h1)
#define KT1  16              // layer1: 8 (W_ih1) + 8 (W_hh1)
#define L0_FRAGS (NT * KT0)  // 432
#define L1_FRAGS (NT * KT1)  // 768
#define TOT_FRAGS (L0_FRAGS + L1_FRAGS)  // 1200 x 1KB
#define WQ_COPY_BYTES (TOT_FRAGS * 1024) // 1.2288 MB
#define N_COPIES 4

#define NBLK 128
#define TPB  1024            // 16 waves; wave j owns gate-triple j
#define ROWS 16
#define PITCH0 320           // 40 x 16B chunks (multiple of 8 -> XOR swizzle ok)
#define PITCH1 576           // 72 x 16B chunks

// XOR swizzle: element e of row r lives at physical element SWZ(r,e).
// Bijective within each row (chunk group of 8), makes the 16-row b128
// A-fragment read conflict-free (2 lanes/bank only).
#define SWZ(r, e) ((((((e) >> 3) ^ ((r) & 7)) << 3)) | ((e) & 7))

using frag_ab = __attribute__((ext_vector_type(8))) short;  // 8 x bf16
using f32x4   = __attribute__((ext_vector_type(4))) float;

__device__ __forceinline__ unsigned short f2bf(float f) {
  unsigned int u = __float_as_uint(f);
  u = (u + 0x7fffu + ((u >> 16) & 1u)) >> 16;  // RNE
  return (unsigned short)u;
}
__device__ __forceinline__ float sigmoidf_(float v) {
  return 1.f / (1.f + __expf(-v));
}
__device__ __forceinline__ float tanhf_(float v) {
  float a = fabsf(v);
  float e = __expf(-2.f * a);
  float r = (1.f - e) / (1.f + e);
  return v < 0.f ? -r : r;
}
__device__ __forceinline__ f32x4 mfma16(frag_ab a, frag_ab b, f32x4 c) {
  return __builtin_amdgcn_mfma_f32_16x16x32_bf16(a, b, c, 0, 0, 0);
}

// ---------------------------------------------------------------------------
// Prologue: fp32 weights -> bf16 MFMA B-fragments, written to 4 copies
// (different physical addresses -> spreads L2 slice load across blocks).
// ---------------------------------------------------------------------------
__global__ __launch_bounds__(256) void repack_w(
    const float* __restrict__ Wih0, const float* __restrict__ Whh0,
    const float* __restrict__ Wih1, const float* __restrict__ Whh1,
    unsigned short* __restrict__ wq)
{
  int g = blockIdx.x * 256 + threadIdx.x;
  if (g >= TOT_FRAGS * 64) return;
  int f = g >> 6;
  int L = g & 63;
  int q = L >> 4, c16 = L & 15;
  unsigned short v[8];
  if (f < L0_FRAGS) {
    int n = f / KT0, kt = f - n * KT0;
    int col = n * 16 + c16;
    if (kt == 0) {
      #pragma unroll
      for (int j = 0; j < 8; ++j) {
        int k = q * 8 + j;
        v[j] = (k < IN_DIM) ? f2bf(Wih0[col * IN_DIM + k]) : (unsigned short)0;
      }
    } else {
      int kb = (kt - 1) * 32 + q * 8;
      #pragma unroll
      for (int j = 0; j < 8; ++j) v[j] = f2bf(Whh0[col * HID + kb + j]);
    }
  } else {
    int f1 = f - L0_FRAGS;
    int n = f1 / KT1, kt = f1 - n * KT1;
    int col = n * 16 + c16;
    const float* __restrict__ W = (kt < 8) ? Wih1 : Whh1;
    int kb = (kt & 7) * 32 + q * 8;
    #pragma unroll
    for (int j = 0; j < 8; ++j) v[j] = f2bf(W[col * HID + kb + j]);
  }
  frag_ab pv;
  #pragma unroll
  for (int j = 0; j < 8; ++j) pv[j] = (short)v[j];
  #pragma unroll
  for (int cp = 0; cp < N_COPIES; ++cp)
    *(frag_ab*)((char*)wq + (size_t)cp * WQ_COPY_BYTES +
                ((size_t)f << 10) + (size_t)(L << 4)) = pv;
}

// ---------------------------------------------------------------------------
// Persistent fused 2-layer GRU + FC head (R3 structure): depth-5 register
// ring of B-frag triples via asm global_load_dwordx4, in-order vmcnt waits,
// raw s_barrier. New: per-block k-phase rotation + wq copy select (kills
// cross-block L2 lockstep), XOR-swizzled LDS (kills bank conflicts),
// 82KB LDS (forces 1 block/CU).
// ---------------------------------------------------------------------------
__global__ __launch_bounds__(TPB, 4) void gru_fused(
    const float* __restrict__ x,
    const float* __restrict__ bih0, const float* __restrict__ bhh0,
    const float* __restrict__ bih1, const float* __restrict__ bhh1,
    const float* __restrict__ fcw,  const float* __restrict__ fcb,
    const unsigned short* __restrict__ wq,
    float* __restrict__ out)
{
  __shared__ __align__(16) unsigned short A0[2][ROWS][PITCH0]; // [x pad32 | h1]
  __shared__ __align__(16) unsigned short A1[2][ROWS][PITCH1]; // [h1n | h2 | pad]
  __shared__ float h2fc[ROWS][257];
  __shared__ float pad[2200];   // LDS pad -> 82.6 KB total -> 1 block/CU

  const int tid  = threadIdx.x;
  const int wave = tid >> 6;          // 0..15 = col-group
  const int lane = tid & 63;
  const int q    = lane >> 4;
  const int c16  = lane & 15;
  const int sw   = c16 & 7;           // swizzle key for A-frag reads
  const int brow0 = blockIdx.x * ROWS;
  const uint32_t lane16 = (uint32_t)(lane << 4);
  // per-block k-phase rotation (de-lockstep the L2 stream)
  const int r0 = blockIdx.x % KT0;
  const int r1 = (blockIdx.x * 5) & 15;

  if (tid == 0) { ((volatile float*)pad)[0] = 0.f; ((volatile float*)pad)[2199] = 0.f; }

  for (int i = tid; i < 2 * ROWS * PITCH0; i += TPB) (&A0[0][0][0])[i] = 0;
  for (int i = tid; i < 2 * ROWS * PITCH1; i += TPB) (&A1[0][0][0])[i] = 0;

  const int c = wave * 16 + c16;      // this lane's h-column (0..255)
  const float l0_brc = bih0[c]           + bhh0[c];
  const float l0_bzc = bih0[HID + c]     + bhh0[HID + c];
  const float l0_bni = bih0[2*HID + c];
  const float l0_bnh = bhh0[2*HID + c];
  const float l1_brc = bih1[c]           + bhh1[c];
  const float l1_bzc = bih1[HID + c]     + bhh1[HID + c];
  const float l1_bni = bih1[2*HID + c];
  const float l1_bnh = bhh1[2*HID + c];

  // stage x_0 into A0[0] (swizzled)
  if (lane < IN_DIM)
    A0[0][wave][SWZ(wave, lane)] = f2bf(x[(size_t)(brow0 + wave) * IN_DIM + lane]);
  __syncthreads();   // init barrier

  // per-wave fragment-stream byte bases (copy-selected)
  const uint32_t cpo = (uint32_t)(blockIdx.x & (N_COPIES - 1)) * (uint32_t)WQ_COPY_BYTES;
  const uint32_t b0r = cpo + (uint32_t)(( wave       * KT0) << 10);
  const uint32_t b0z = cpo + (uint32_t)(((16 + wave) * KT0) << 10);
  const uint32_t b0n = cpo + (uint32_t)(((32 + wave) * KT0) << 10);
  const uint32_t b1r = cpo + (uint32_t)((L0_FRAGS +  wave       * KT1) << 10);
  const uint32_t b1z = cpo + (uint32_t)((L0_FRAGS + (16 + wave) * KT1) << 10);
  const uint32_t b1n = cpo + (uint32_t)((L0_FRAGS + (32 + wave) * KT1) << 10);

  frag_ab rr_[5], rz_[5], rn_[5];     // depth-5 register ring
  float h1m[4] = {0.f, 0.f, 0.f, 0.f};
  float h2m[4] = {0.f, 0.f, 0.f, 0.f};
  uint32_t xvu = 0;

#define ISSUE3(sl, oR, oZ, oN)                                              \
  asm volatile("global_load_dwordx4 %0, %3, %6\n\t"                         \
               "global_load_dwordx4 %1, %4, %6\n\t"                         \
               "global_load_dwordx4 %2, %5, %6"                             \
               : "=&v"(rr_[sl]), "=&v"(rz_[sl]), "=&v"(rn_[sl])             \
               : "v"((uint32_t)(oR)), "v"((uint32_t)(oZ)),                  \
                 "v"((uint32_t)(oN)), "s"(wq)                               \
               : "memory")
#define WAIT3(sl, NSTR)                                                     \
  asm volatile("s_waitcnt vmcnt(" NSTR ")"                                  \
               : "+v"(rr_[sl]), "+v"(rz_[sl]), "+v"(rn_[sl]) :: "memory")
#define BARRIER() asm volatile("s_waitcnt lgkmcnt(0)\n\ts_barrier" ::: "memory")

  // prologue: fill ring with L0 triples, phases r0, r0+1, ... (mod 9)
  #pragma unroll
  for (int i = 0; i < 5; ++i) {
    int pk = r0 + i; if (pk >= KT0) pk -= KT0;
    const uint32_t o = (uint32_t)pk * 1024 + lane16;
    ISSUE3(i, b0r + o, b0z + o, b0n + o);
  }

  for (int t = 0; t < T_STEPS; ++t) {
    const int p = t & 1, np = p ^ 1;

    // ================= Layer 0 (9 triples, rotated phase) =================
    f32x4 ar = {0,0,0,0}, az = {0,0,0,0}, anx = {0,0,0,0}, anh = {0,0,0,0};
    #pragma unroll
    for (int i = 0; i < KT0; ++i) {
      const int sl = i % 5;
      if (i == 0)      { WAIT3(sl, "12"); }
      else if (i <= 5) { WAIT3(sl, "13"); }   // x-load sits in the queue
      else             { WAIT3(sl, "12"); }
      int pk = r0 + i; if (pk >= KT0) pk -= KT0;
      const frag_ab a = *(const frag_ab*)&A0[p][c16][((4 * pk + q) ^ sw) * 8];
      ar = mfma16(a, rr_[sl], ar);
      az = mfma16(a, rz_[sl], az);
      if (pk == 0) anx = mfma16(a, rn_[sl], anx);
      else         anh = mfma16(a, rn_[sl], anh);
      if (i + 5 < KT0) {              // issue L0 phases i+5
        int pk2 = r0 + i + 5; if (pk2 >= KT0) pk2 -= KT0;
        const uint32_t o = (uint32_t)pk2 * 1024 + lane16;
        ISSUE3(sl, b0r + o, b0z + o, b0n + o);
      } else {                        // issue L1 phases 0..4
        const int pk2 = (r1 + i - 4) & 15;
        const uint32_t o = (uint32_t)pk2 * 1024 + lane16;
        ISSUE3(sl, b1r + o, b1z + o, b1n + o);
      }
      if (i == 0) {                   // x_{t+1} prefetch
        const int t1 = (t < T_STEPS - 1) ? t + 1 : t;
        const uint32_t xoff =
            (uint32_t)(((t1 * BATCH + brow0 + wave) * IN_DIM
                        + (lane < IN_DIM ? lane : IN_DIM - 1)) * 4);
        asm volatile("global_load_dword %0, %1, %2"
                     : "=&v"(xvu) : "v"(xoff), "s"(x) : "memory");
      }
    }
    // ---- L0 epilogue ----
    asm volatile("s_waitcnt vmcnt(24)" : "+v"(xvu) :: "memory"); // x done
    if (lane < IN_DIM)
      A0[np][wave][SWZ(wave, lane)] = f2bf(__uint_as_float(xvu));
    #pragma unroll
    for (int rrI = 0; rrI < 4; ++rrI) {
      const int row = q * 4 + rrI;   // C/D: row=(lane>>4)*4+reg, col=lane&15
      float rg = sigmoidf_(ar[rrI] + l0_brc);
      float zg = sigmoidf_(az[rrI] + l0_bzc);
      float ng = tanhf_(anx[rrI] + l0_bni + rg * (anh[rrI] + l0_bnh));
      float hnew = (1.f - zg) * ng + zg * h1m[rrI];
      h1m[rrI] = hnew;
      unsigned short hb = f2bf(hnew);
      A0[np][row][SWZ(row, 32 + c)] = hb;   // next step's layer-0 A
      A1[p][row][SWZ(row, c)]       = hb;   // this step's layer-1 A
    }
    BARRIER();   // the ONE barrier per step; vm queue stays loaded across it

    // ================= Layer 1 (16 triples, rotated phase) =================
    ar = (f32x4){0,0,0,0}; az = (f32x4){0,0,0,0};
    anx = (f32x4){0,0,0,0}; anh = (f32x4){0,0,0,0};
    #pragma unroll
    for (int i = 0; i < KT1; ++i) {
      const int sl = (9 + i) % 5;
      WAIT3(sl, "12");
      const int pk = (r1 + i) & 15;
      const frag_ab a = *(const frag_ab*)&A1[p][c16][((4 * pk + q) ^ sw) * 8];
      ar = mfma16(a, rr_[sl], ar);
      az = mfma16(a, rz_[sl], az);
      if (pk < 8) anx = mfma16(a, rn_[sl], anx);   // W_ih1 @ h1_new
      else        anh = mfma16(a, rn_[sl], anh);   // W_hh1 @ h2
      if (i < 11) {                   // issue L1 phases i+5
        const int pk2 = (r1 + i + 5) & 15;
        const uint32_t o = (uint32_t)pk2 * 1024 + lane16;
        ISSUE3(sl, b1r + o, b1z + o, b1n + o);
      } else {                        // issue next step's L0 phases 0..4
        int pk2 = r0 + i - 11; if (pk2 >= KT0) pk2 -= KT0;
        const uint32_t o = (uint32_t)pk2 * 1024 + lane16;
        ISSUE3(sl, b0r + o, b0z + o, b0n + o);
      }
    }
    // ---- L1 epilogue ----
    #pragma unroll
    for (int rrI = 0; rrI < 4; ++rrI) {
      const int row = q * 4 + rrI;
      float rg = sigmoidf_(ar[rrI] + l1_brc);
      float zg = sigmoidf_(az[rrI] + l1_bzc);
      float ng = tanhf_(anx[rrI] + l1_bni + rg * (anh[rrI] + l1_bnh));
      float hnew = (1.f - zg) * ng + zg * h2m[rrI];
      h2m[rrI] = hnew;
      A1[np][row][SWZ(row, HID + c)] = f2bf(hnew);  // next step's h2 A-part
      if (t == T_STEPS - 1) h2fc[row][c] = hnew;
    }
    // no end-of-step barrier (next step's mid-step barrier orders everything)
  }

  asm volatile("s_waitcnt vmcnt(0)" ::: "memory");  // drain tail prefetches
  __syncthreads();

  // ---- FC head ----
  if (tid < ROWS * 4) {
    int row = tid >> 2, o = tid & 3;
    const float* wrow = &fcw[o * HID];
    float acc = fcb[o];
    #pragma unroll 8
    for (int k = 0; k < HID; ++k) acc += h2fc[row][k] * wrow[k];
    float sg = 1.f / (1.f + __expf(-acc));
    out[(size_t)(brow0 + row) * 4 + o] = sg * 2.f - 1.f;
  }
#undef ISSUE3
#undef WAIT3
#undef BARRIER
}

extern "C" void kernel_launch(void* const* d_in, const int* in_sizes, int n_in,
                              void* d_out, int out_size, void* d_ws, size_t ws_size,
                              hipStream_t stream) {
  const float* x    = (const float*)d_in[0];
  const float* Wih0 = (const float*)d_in[1];
  const float* Whh0 = (const float*)d_in[2];
  const float* bih0 = (const float*)d_in[3];
  const float* bhh0 = (const float*)d_in[4];
  const float* Wih1 = (const float*)d_in[5];
  const float* Whh1 = (const float*)d_in[6];
  const float* bih1 = (const float*)d_in[7];
  const float* bhh1 = (const float*)d_in[8];
  const float* fcw  = (const float*)d_in[9];
  const float* fcb  = (const float*)d_in[10];
  unsigned short* wq = (unsigned short*)d_ws;  // 4 copies x 1.2288 MB = 4.9 MB

  repack_w<<<(TOT_FRAGS * 64 + 255) / 256, 256, 0, stream>>>(Wih0, Whh0, Wih1, Whh1, wq);
  gru_fused<<<NBLK, TPB, 0, stream>>>(x, bih0, bhh0, bih1, bhh1, fcw, fcb, wq,
                                      (float*)d_out);
}